// Round 5
// baseline (944.627 us; speedup 1.0000x reference)
//
#include <hip/hip_runtime.h>
#include <hip/hip_bf16.h>
#include <math.h>

typedef unsigned short u16;
typedef unsigned int   u32;
typedef float f32x4 __attribute__((ext_vector_type(4)));
typedef short s16x8 __attribute__((ext_vector_type(8)));
typedef __bf16 bf16x8 __attribute__((ext_vector_type(8)));

#define AS1 __attribute__((address_space(1)))
#define AS3 __attribute__((address_space(3)))

__device__ __forceinline__ float bf2f(u16 v){ u32 u = ((u32)v) << 16; return __builtin_bit_cast(float, u); }
__device__ __forceinline__ u16 f2bf(float f){
  u32 u = __builtin_bit_cast(u32, f);
  u += 0x7FFFu + ((u >> 16) & 1u);
  return (u16)(u >> 16);
}

// builtin MFMA — compiler manages all hazards/waitcnts
__device__ __forceinline__ void mfma16x16x32(f32x4& d, s16x8 a, s16x8 b){
  d = __builtin_amdgcn_mfma_f32_16x16x32_bf16(
        __builtin_bit_cast(bf16x8, a), __builtin_bit_cast(bf16x8, b), d, 0, 0, 0);
}

// ---------------------------------------------------------------------------
// Weight transpose + f32->bf16: in f32 [R][C] -> out bf16 [C][R]
// ---------------------------------------------------------------------------
__launch_bounds__(256)
__global__ void transpose_w(const float* __restrict__ in, u16* __restrict__ outp, int R, int C)
{
  __shared__ float tile[32][33];
  const int tx = threadIdx.x & 31;
  const int ty = threadIdx.x >> 5;           // 0..7
  const int r0 = blockIdx.y * 32;
  const int c0 = blockIdx.x * 32;
  #pragma unroll
  for (int yy = ty; yy < 32; yy += 8) tile[yy][tx] = in[(size_t)(r0 + yy) * C + c0 + tx];
  __syncthreads();
  #pragma unroll
  for (int yy = ty; yy < 32; yy += 8) outp[(size_t)(c0 + yy) * R + r0 + tx] = f2bf(tile[tx][yy]);
}

// ---------------------------------------------------------------------------
// LayerNorm over C=512 (f32 in, bf16 out); optional fused shift+window gather
// One wave per token, 4 tokens per 256-thread block.
// ---------------------------------------------------------------------------
template<bool SHIFTWIN>
__launch_bounds__(256)
__global__ void ln_win(const float* __restrict__ x, const float* __restrict__ sc,
                       const float* __restrict__ bi, u16* __restrict__ out)
{
  const int wave = threadIdx.x >> 6;
  const int lane = threadIdx.x & 63;
  const int tok  = blockIdx.x * 4 + wave;
  const float* src;
  if constexpr (SHIFTWIN) {
    int b = tok / 3136; int rem = tok - b * 3136;
    int win = rem / 49; int n = rem - win * 49;
    int wh = win >> 3, ww = win & 7;
    int i = n / 7, j = n - i * 7;
    int hh = wh * 7 + i + 3; if (hh >= 56) hh -= 56;
    int wp = ww * 7 + j + 3; if (wp >= 56) wp -= 56;
    src = x + ((size_t)b * 3136 + (size_t)hh * 56 + wp) * 512;
  } else {
    src = x + (size_t)tok * 512;
  }
  f32x4 v0 = *(const f32x4*)(src + lane * 8);
  f32x4 v1 = *(const f32x4*)(src + lane * 8 + 4);
  float f[8] = {v0[0], v0[1], v0[2], v0[3], v1[0], v1[1], v1[2], v1[3]};
  float s1 = 0.f, s2 = 0.f;
  #pragma unroll
  for (int ii = 0; ii < 8; ++ii){ s1 += f[ii]; s2 += f[ii] * f[ii]; }
  #pragma unroll
  for (int d = 1; d < 64; d <<= 1){ s1 += __shfl_xor(s1, d); s2 += __shfl_xor(s2, d); }
  float mean = s1 * (1.f / 512.f);
  float var  = s2 * (1.f / 512.f) - mean * mean;
  float rs = rsqrtf(var + 1e-5f);
  s16x8 o;
  #pragma unroll
  for (int ii = 0; ii < 8; ++ii){
    int cc = lane * 8 + ii;
    float t = (f[ii] - mean) * rs * sc[cc] + bi[cc];
    o[ii] = (short)f2bf(t);
  }
  *(s16x8*)(out + (size_t)tok * 512 + lane * 8) = o;
}

// ---------------------------------------------------------------------------
// MFMA GEMM: C[M,N] = A[M,K] @ Bt[N,K]^T + bias(f32), 128x128 tile, BK=32,
// 4 waves (2x2 of 64x64), global_load_lds width-16 staging (m97 structure).
// MODE: 0 = bf16 store (outb)
//       1 = exact GELU, bf16 store (outb)
//       2 = window-reverse+unshift scatter, f32 store outf = residf + v
//       3 = f32 store outf = residf + v (outf may alias residf; same-thread R/W)
// ---------------------------------------------------------------------------
template<int MODE>
__launch_bounds__(256, 2)
__global__ void gemm_bt(const u16* __restrict__ A, const u16* __restrict__ Bt,
                        const float* __restrict__ bias, u16* __restrict__ outb,
                        float* outf, const float* residf, int N, int K)
{
  __shared__ u16 As[128 * 32];
  __shared__ u16 Bs[128 * 32];
  const int tid  = threadIdx.x;
  const int lane = tid & 63;
  const int wave = tid >> 6;
  const int cc = lane & 15, g = lane >> 4;
  const int m0 = blockIdx.y * 128;
  const int n0 = blockIdx.x * 128;
  const int wr = wave >> 1, wc = wave & 1;

  // staging geometry: tile = 4096 elems, 8 chunks of 512 elems (1KB); wave w stages chunks 2w, 2w+1
  const int ea0 = wave * 1024 + lane * 8;
  const int ea1 = ea0 + 512;
  const int r0 = ea0 >> 5, c0 = ea0 & 31;
  const int r1 = ea1 >> 5, c1 = ea1 & 31;
  const size_t aRow0 = (size_t)(m0 + r0) * K;
  const size_t aRow1 = (size_t)(m0 + r1) * K;
  const size_t bRow0 = (size_t)(n0 + r0) * K;
  const size_t bRow1 = (size_t)(n0 + r1) * K;

  f32x4 acc[4][4] = {};

  for (int k0 = 0; k0 < K; k0 += 32) {
    __builtin_amdgcn_global_load_lds((const AS1 u32*)(A  + aRow0 + k0 + c0), (AS3 u32*)(As + wave * 1024),       16, 0, 0);
    __builtin_amdgcn_global_load_lds((const AS1 u32*)(A  + aRow1 + k0 + c1), (AS3 u32*)(As + wave * 1024 + 512), 16, 0, 0);
    __builtin_amdgcn_global_load_lds((const AS1 u32*)(Bt + bRow0 + k0 + c0), (AS3 u32*)(Bs + wave * 1024),       16, 0, 0);
    __builtin_amdgcn_global_load_lds((const AS1 u32*)(Bt + bRow1 + k0 + c1), (AS3 u32*)(Bs + wave * 1024 + 512), 16, 0, 0);
    __syncthreads();
    s16x8 af[4], bfr[4];
    #pragma unroll
    for (int mi = 0; mi < 4; ++mi) af[mi]  = *(const s16x8*)&As[(wr * 64 + mi * 16 + cc) * 32 + g * 8];
    #pragma unroll
    for (int ni = 0; ni < 4; ++ni) bfr[ni] = *(const s16x8*)&Bs[(wc * 64 + ni * 16 + cc) * 32 + g * 8];
    #pragma unroll
    for (int mi = 0; mi < 4; ++mi)
      #pragma unroll
      for (int ni = 0; ni < 4; ++ni)
        mfma16x16x32(acc[mi][ni], af[mi], bfr[ni]);
    __syncthreads();
  }

  float bval[4];
  #pragma unroll
  for (int ni = 0; ni < 4; ++ni) bval[ni] = bias[n0 + wc * 64 + ni * 16 + cc];

  #pragma unroll
  for (int mi = 0; mi < 4; ++mi) {
    #pragma unroll
    for (int r = 0; r < 4; ++r) {
      const int row = m0 + wr * 64 + mi * 16 + g * 4 + r;
      size_t obase;
      if constexpr (MODE == 2) {
        int b = row / 3136; int rem = row - b * 3136;
        int win = rem / 49; int n = rem - win * 49;
        int wh = win >> 3, ww = win & 7;
        int i = n / 7, j = n - i * 7;
        int hh = wh * 7 + i + 3; if (hh >= 56) hh -= 56;
        int wp = ww * 7 + j + 3; if (wp >= 56) wp -= 56;
        obase = ((size_t)b * 3136 + (size_t)hh * 56 + wp) * 512;
      } else {
        obase = (size_t)row * N;
      }
      #pragma unroll
      for (int ni = 0; ni < 4; ++ni) {
        const int col = n0 + wc * 64 + ni * 16 + cc;
        float v = acc[mi][ni][r] + bval[ni];
        if constexpr (MODE == 0) {
          outb[obase + col] = f2bf(v);
        } else if constexpr (MODE == 1) {
          outb[obase + col] = f2bf(0.5f * v * (1.0f + erff(v * 0.7071067811865475f)));
        } else {
          outf[obase + col] = residf[obase + col] + v;
        }
      }
    }
  }
}

// ---------------------------------------------------------------------------
// Windowed attention: one wave per (window, head). N=49 (padded 64), HD=32.
// qkv layout per token (chunk-local): [Q(16x32) | K(16x32) | V(16x32)] = 1536.
// wgBase: first global window of this chunk; o indexed by GLOBAL window.
// ---------------------------------------------------------------------------
__device__ __forceinline__ int regcls(int a){ return a < 49 ? 0 : (a < 53 ? 1 : 2); }

__launch_bounds__(64)
__global__ void attn49(const u16* __restrict__ qkv, const float* __restrict__ rpbt,
                       u16* __restrict__ o, int wgBase)
{
  const int unit = blockIdx.x;
  const int wgl = unit >> 4;          // chunk-local window
  const int wg  = wgBase + wgl;       // global window 0..1023
  const int h  = unit & 15;           // head
  const int win = wg & 63;
  const int wh = win >> 3, ww = win & 7;
  const int l = threadIdx.x;
  const int cc = l & 15, g = l >> 4;

  __shared__ u16 P[64 * 72];          // softmax probs, padded stride 72
  __shared__ u16 Vt[32 * 72];         // V transposed [d][k], padded stride 72

  const u16* qb = qkv + (size_t)wgl * 49 * 1536 + h * 32;

  s16x8 qf[4], kf[4];
  #pragma unroll
  for (int mi = 0; mi < 4; ++mi){ int m = mi * 16 + cc; int t = m < 49 ? m : 48;
    qf[mi] = *(const s16x8*)(qb + (size_t)t * 1536 + g * 8); }
  #pragma unroll
  for (int ni = 0; ni < 4; ++ni){ int n = ni * 16 + cc; int t = n < 49 ? n : 48;
    kf[ni] = *(const s16x8*)(qb + 512 + (size_t)t * 1536 + g * 8); }

  { // stage V^T: lane l owns k-row l (clamped)
    int t = l < 49 ? l : 48;
    const u16* vp = qb + 1024 + (size_t)t * 1536;
    s16x8 va = *(const s16x8*)(vp);
    s16x8 vb_ = *(const s16x8*)(vp + 8);
    s16x8 vc = *(const s16x8*)(vp + 16);
    s16x8 vd = *(const s16x8*)(vp + 24);
    #pragma unroll
    for (int d = 0; d < 8; ++d){
      Vt[(d     ) * 72 + l] = (u16)va[d];
      Vt[(d +  8) * 72 + l] = (u16)vb_[d];
      Vt[(d + 16) * 72 + l] = (u16)vc[d];
      Vt[(d + 24) * 72 + l] = (u16)vd[d];
    }
  }

  f32x4 s[4][4] = {};
  #pragma unroll
  for (int mi = 0; mi < 4; ++mi)
    #pragma unroll
    for (int ni = 0; ni < 4; ++ni)
      mfma16x16x32(s[mi][ni], qf[mi], kf[ni]);

  // per-lane column metadata (n = ni*16 + cc)
  int xn[4], yn[4], ncl[4]; bool nval[4];
  #pragma unroll
  for (int ni = 0; ni < 4; ++ni){
    int n = ni * 16 + cc; nval[ni] = (n < 49);
    int t = n < 49 ? n : 48;
    yn[ni] = t / 7; xn[ni] = t - yn[ni] * 7;
    ncl[ni] = regcls(wh * 7 + yn[ni]) * 3 + regcls(ww * 7 + xn[ni]);
  }

  const float SCL = 0.17677669529663687f;   // 32^-0.5
  #pragma unroll
  for (int mi = 0; mi < 4; ++mi){
    #pragma unroll
    for (int r = 0; r < 4; ++r){
      int m = mi * 16 + g * 4 + r;
      int mt = m < 49 ? m : 48;
      int ym = mt / 7, xm = mt - ym * 7;
      int mcl = regcls(wh * 7 + ym) * 3 + regcls(ww * 7 + xm);
      float vals[4];
      #pragma unroll
      for (int ni = 0; ni < 4; ++ni){
        // reference index quirk: idx = (dx+6)*13 + (dy+6), x = tok%7, y = tok/7
        int idx = (xm - xn[ni] + 6) * 13 + (ym - yn[ni] + 6);
        float v = s[mi][ni][r] * SCL + rpbt[idx * 16 + h];
        if (ncl[ni] != mcl) v -= 100.f;
        if (!nval[ni]) v = -1e9f;
        vals[ni] = v;
      }
      float mx = fmaxf(fmaxf(vals[0], vals[1]), fmaxf(vals[2], vals[3]));
      #pragma unroll
      for (int d2 = 1; d2 < 16; d2 <<= 1) mx = fmaxf(mx, __shfl_xor(mx, d2));
      float e[4]; float sm = 0.f;
      #pragma unroll
      for (int ni = 0; ni < 4; ++ni){ e[ni] = __expf(vals[ni] - mx); sm += e[ni]; }
      #pragma unroll
      for (int d2 = 1; d2 < 16; d2 <<= 1) sm += __shfl_xor(sm, d2);
      float inv = 1.f / sm;
      #pragma unroll
      for (int ni = 0; ni < 4; ++ni) P[m * 72 + ni * 16 + cc] = f2bf(e[ni] * inv);
    }
  }
  __syncthreads();

  f32x4 oa[4][2] = {};
  #pragma unroll
  for (int kk = 0; kk < 2; ++kk){
    s16x8 pa[4], vb[2];
    #pragma unroll
    for (int mi = 0; mi < 4; ++mi) pa[mi] = *(const s16x8*)&P[(mi * 16 + cc) * 72 + kk * 32 + g * 8];
    #pragma unroll
    for (int ni = 0; ni < 2; ++ni) vb[ni] = *(const s16x8*)&Vt[(ni * 16 + cc) * 72 + kk * 32 + g * 8];
    #pragma unroll
    for (int mi = 0; mi < 4; ++mi)
      #pragma unroll
      for (int ni = 0; ni < 2; ++ni)
        mfma16x16x32(oa[mi][ni], pa[mi], vb[ni]);
  }

  const size_t tb = (size_t)wg * 49;
  #pragma unroll
  for (int mi = 0; mi < 4; ++mi)
    #pragma unroll
    for (int r = 0; r < 4; ++r){
      int m = mi * 16 + g * 4 + r;
      if (m < 49){
        size_t ob = (tb + m) * 512 + h * 32;
        o[ob + cc]      = f2bf(oa[mi][0][r]);
        o[ob + 16 + cc] = f2bf(oa[mi][1][r]);
      }
    }
}

// ---------------------------------------------------------------------------
// Launch — f32 in/out, bf16 intermediates, ws-adaptive M-chunking
// ---------------------------------------------------------------------------
extern "C" void kernel_launch(void* const* d_in, const int* in_sizes, int n_in,
                              void* d_out, int out_size, void* d_ws, size_t ws_size,
                              hipStream_t stream)
{
  const float* x      = (const float*)d_in[0];
  const float* ln1_s  = (const float*)d_in[1];
  const float* ln1_b  = (const float*)d_in[2];
  const float* qkv_w  = (const float*)d_in[3];
  const float* qkv_b  = (const float*)d_in[4];
  const float* rpbt   = (const float*)d_in[5];
  const float* proj_w = (const float*)d_in[6];
  const float* proj_b = (const float*)d_in[7];
  const float* ln2_s  = (const float*)d_in[8];
  const float* ln2_b  = (const float*)d_in[9];
  const float* fc1_w  = (const float*)d_in[10];
  const float* fc1_b  = (const float*)d_in[11];
  const float* fc2_w  = (const float*)d_in[12];
  const float* fc2_b  = (const float*)d_in[13];
  float* outF = (float*)d_out;

  const size_t BUFA_B = 51380224ull;             // 50176*512*2 (bf16)
  const size_t WTS_B  = 6291456ull;              // transposed bf16 weights
  // pick chunk count: bufB = (50176/CH)*2048*2 bytes
  int CH = 8;
  for (int c : {1, 2, 4}) {
    size_t bufb = (50176ull / c) * 4096ull;
    if (ws_size >= BUFA_B + bufb + WTS_B) { CH = c; break; }
  }
  const int MCH = 50176 / CH;                    // rows per chunk (multiple of 128)
  const int TCH = MCH / 128;                     // row-tiles per chunk
  const int WCH = 1024 / CH;                     // windows per chunk
  const size_t BUFB_B = (size_t)MCH * 4096ull;

  char* w = (char*)d_ws;
  u16* bufA = (u16*)(w);                         // hwin -> attn_out -> ln2_out (bf16, full)
  u16* bufB = (u16*)(w + BUFA_B);                // per-chunk qkv / gelu act (bf16, union)
  u16* qkvT  = (u16*)(w + BUFA_B + BUFB_B);
  u16* projT = qkvT + 786432;
  u16* fc1T  = projT + 262144;
  u16* fc2T  = fc1T + 1048576;

  // weight transposes + f32->bf16 ([K,N] -> [N,K])
  transpose_w<<<dim3(1536/32, 512/32),  256, 0, stream>>>(qkv_w,  qkvT, 512, 1536);
  transpose_w<<<dim3( 512/32, 512/32),  256, 0, stream>>>(proj_w, projT, 512, 512);
  transpose_w<<<dim3(2048/32, 512/32),  256, 0, stream>>>(fc1_w,  fc1T, 512, 2048);
  transpose_w<<<dim3( 512/32, 2048/32), 256, 0, stream>>>(fc2_w,  fc2T, 2048, 512);

  // LN1 + cyclic shift + window partition (f32 -> bf16 windowed)
  ln_win<true><<<12544, 256, 0, stream>>>(x, ln1_s, ln1_b, bufA);

  // chunked: QKV GEMM -> windowed attention (attn writes back into bufA rows of its chunk)
  for (int c = 0; c < CH; ++c) {
    gemm_bt<0><<<dim3(12, TCH), 256, 0, stream>>>(bufA + (size_t)c * MCH * 512, qkvT, qkv_b,
                                                  bufB, nullptr, nullptr, 1536, 512);
    attn49<<<WCH * 16, 64, 0, stream>>>(bufB, rpbt, bufA, c * WCH);
  }

  // proj GEMM + window reverse + unshift + residual(x) -> x1 (f32, in d_out)
  gemm_bt<2><<<dim3(4, 392), 256, 0, stream>>>(bufA, projT, proj_b, nullptr, outF, x, 512, 512);

  // LN2 (reads f32 x1 from d_out)
  ln_win<false><<<12544, 256, 0, stream>>>(outF, ln2_s, ln2_b, bufA);

  // chunked: FC1+GELU -> FC2+residual (x1 aliased in d_out, same-thread R-then-W)
  for (int c = 0; c < CH; ++c) {
    gemm_bt<1><<<dim3(16, TCH), 256, 0, stream>>>(bufA + (size_t)c * MCH * 512, fc1T, fc1_b,
                                                  bufB, nullptr, nullptr, 2048, 512);
    gemm_bt<3><<<dim3(4, TCH), 256, 0, stream>>>(bufB, fc2T, fc2_b, nullptr,
                                                 outF + (size_t)c * MCH * 512,
                                                 outF + (size_t)c * MCH * 512, 512, 2048);
  }
}

// Round 6
// 936.430 us; speedup vs baseline: 1.0088x; 1.0088x over previous
//
#include <hip/hip_runtime.h>
#include <hip/hip_bf16.h>
#include <math.h>

typedef unsigned short u16;
typedef unsigned int   u32;
typedef float f32x4 __attribute__((ext_vector_type(4)));
typedef short s16x8 __attribute__((ext_vector_type(8)));
typedef __bf16 bf16x8 __attribute__((ext_vector_type(8)));

#define AS1 __attribute__((address_space(1)))
#define AS3 __attribute__((address_space(3)))

__device__ __forceinline__ float bf2f(u16 v){ u32 u = ((u32)v) << 16; return __builtin_bit_cast(float, u); }
__device__ __forceinline__ u16 f2bf(float f){
  u32 u = __builtin_bit_cast(u32, f);
  u += 0x7FFFu + ((u >> 16) & 1u);
  return (u16)(u >> 16);
}

// builtin MFMA — compiler manages all hazards/waitcnts
__device__ __forceinline__ void mfma16x16x32(f32x4& d, s16x8 a, s16x8 b){
  d = __builtin_amdgcn_mfma_f32_16x16x32_bf16(
        __builtin_bit_cast(bf16x8, a), __builtin_bit_cast(bf16x8, b), d, 0, 0, 0);
}

// ---------------------------------------------------------------------------
// Weight transpose + f32->bf16: in f32 [R][C] -> out bf16 [C][R]
// ---------------------------------------------------------------------------
__launch_bounds__(256)
__global__ void transpose_w(const float* __restrict__ in, u16* __restrict__ outp, int R, int C)
{
  __shared__ float tile[32][33];
  const int tx = threadIdx.x & 31;
  const int ty = threadIdx.x >> 5;           // 0..7
  const int r0 = blockIdx.y * 32;
  const int c0 = blockIdx.x * 32;
  #pragma unroll
  for (int yy = ty; yy < 32; yy += 8) tile[yy][tx] = in[(size_t)(r0 + yy) * C + c0 + tx];
  __syncthreads();
  #pragma unroll
  for (int yy = ty; yy < 32; yy += 8) outp[(size_t)(c0 + yy) * R + r0 + tx] = f2bf(tile[tx][yy]);
}

// ---------------------------------------------------------------------------
// LayerNorm over C=512 (f32 in, bf16 out); optional fused shift+window gather
// One wave per token, 4 tokens per 256-thread block.
// ---------------------------------------------------------------------------
template<bool SHIFTWIN>
__launch_bounds__(256)
__global__ void ln_win(const float* __restrict__ x, const float* __restrict__ sc,
                       const float* __restrict__ bi, u16* __restrict__ out)
{
  const int wave = threadIdx.x >> 6;
  const int lane = threadIdx.x & 63;
  const int tok  = blockIdx.x * 4 + wave;
  const float* src;
  if constexpr (SHIFTWIN) {
    int b = tok / 3136; int rem = tok - b * 3136;
    int win = rem / 49; int n = rem - win * 49;
    int wh = win >> 3, ww = win & 7;
    int i = n / 7, j = n - i * 7;
    int hh = wh * 7 + i + 3; if (hh >= 56) hh -= 56;
    int wp = ww * 7 + j + 3; if (wp >= 56) wp -= 56;
    src = x + ((size_t)b * 3136 + (size_t)hh * 56 + wp) * 512;
  } else {
    src = x + (size_t)tok * 512;
  }
  f32x4 v0 = *(const f32x4*)(src + lane * 8);
  f32x4 v1 = *(const f32x4*)(src + lane * 8 + 4);
  float f[8] = {v0[0], v0[1], v0[2], v0[3], v1[0], v1[1], v1[2], v1[3]};
  float s1 = 0.f, s2 = 0.f;
  #pragma unroll
  for (int ii = 0; ii < 8; ++ii){ s1 += f[ii]; s2 += f[ii] * f[ii]; }
  #pragma unroll
  for (int d = 1; d < 64; d <<= 1){ s1 += __shfl_xor(s1, d); s2 += __shfl_xor(s2, d); }
  float mean = s1 * (1.f / 512.f);
  float var  = s2 * (1.f / 512.f) - mean * mean;
  float rs = rsqrtf(var + 1e-5f);
  s16x8 o;
  #pragma unroll
  for (int ii = 0; ii < 8; ++ii){
    int cc = lane * 8 + ii;
    float t = (f[ii] - mean) * rs * sc[cc] + bi[cc];
    o[ii] = (short)f2bf(t);
  }
  *(s16x8*)(out + (size_t)tok * 512 + lane * 8) = o;
}

// ---------------------------------------------------------------------------
// MFMA GEMM: C[M,N] = A[M,K] @ Bt[N,K]^T + bias(f32), 128x128 tile, BK=32,
// 4 waves (2x2 of 64x64). 2-PHASE double-buffered pipeline (T3-minimum):
//   STAGE(next tile) -> ds_read+MFMA(cur) -> one __syncthreads per tile.
// The barrier's implicit vmcnt(0)/lgkmcnt(0) drain lands AFTER the MFMA work,
// hiding staging latency instead of exposing it (was: drain before compute).
// MODE: 0 = bf16 store (outb)
//       1 = exact GELU, bf16 store (outb)
//       2 = window-reverse+unshift scatter, f32 store outf = residf + v
//       3 = f32 store outf = residf + v (alias ok; same-thread R/W) + XCD swizzle
// ---------------------------------------------------------------------------
template<int MODE>
__launch_bounds__(256, 2)
__global__ void gemm_bt(const u16* __restrict__ A, const u16* __restrict__ Bt,
                        const float* __restrict__ bias, u16* __restrict__ outb,
                        float* outf, const float* residf, int N, int K)
{
  __shared__ u16 As[2][128 * 32];
  __shared__ u16 Bs[2][128 * 32];
  const int tid  = threadIdx.x;
  const int lane = tid & 63;
  const int wave = tid >> 6;
  const int cc = lane & 15, g = lane >> 4;

  int bx = blockIdx.x, by = blockIdx.y;
  if constexpr (MODE == 3) {
    // T1 bijective XCD swizzle (A operand is HBM-resident for FC2): give each
    // XCD a contiguous chunk of the flat grid. Only valid when nwg % 8 == 0.
    int gx = gridDim.x;
    int nwg = gx * gridDim.y;
    if ((nwg & 7) == 0) {
      int orig = by * gx + bx;
      int wgid = (orig & 7) * (nwg >> 3) + (orig >> 3);
      bx = wgid % gx; by = wgid / gx;
    }
  }
  const int m0 = by * 128;
  const int n0 = bx * 128;
  const int wr = wave >> 1, wc = wave & 1;

  // staging geometry: tile = 4096 elems, 8 chunks of 512 elems (1KB); wave w stages chunks 2w, 2w+1
  const int ea0 = wave * 1024 + lane * 8;
  const int ea1 = ea0 + 512;
  const int r0 = ea0 >> 5, c0 = ea0 & 31;
  const int r1 = ea1 >> 5, c1 = ea1 & 31;
  const size_t aRow0 = (size_t)(m0 + r0) * K;
  const size_t aRow1 = (size_t)(m0 + r1) * K;
  const size_t bRow0 = (size_t)(n0 + r0) * K;
  const size_t bRow1 = (size_t)(n0 + r1) * K;

  f32x4 acc[4][4] = {};

  auto stage = [&](int buf, int k0) __attribute__((always_inline)) {
    __builtin_amdgcn_global_load_lds((const AS1 u32*)(A  + aRow0 + k0 + c0), (AS3 u32*)(&As[buf][wave * 1024]),       16, 0, 0);
    __builtin_amdgcn_global_load_lds((const AS1 u32*)(A  + aRow1 + k0 + c1), (AS3 u32*)(&As[buf][wave * 1024 + 512]), 16, 0, 0);
    __builtin_amdgcn_global_load_lds((const AS1 u32*)(Bt + bRow0 + k0 + c0), (AS3 u32*)(&Bs[buf][wave * 1024]),       16, 0, 0);
    __builtin_amdgcn_global_load_lds((const AS1 u32*)(Bt + bRow1 + k0 + c1), (AS3 u32*)(&Bs[buf][wave * 1024 + 512]), 16, 0, 0);
  };

  const int T = K >> 5;
  stage(0, 0);
  __syncthreads();                       // buf0 ready
  int cur = 0;
  for (int t = 0; t < T; ++t) {
    if (t + 1 < T) stage(cur ^ 1, (t + 1) << 5);   // issue next-tile loads FIRST
    s16x8 af[4], bfr[4];
    #pragma unroll
    for (int mi = 0; mi < 4; ++mi) af[mi]  = *(const s16x8*)&As[cur][(wr * 64 + mi * 16 + cc) * 32 + g * 8];
    #pragma unroll
    for (int ni = 0; ni < 4; ++ni) bfr[ni] = *(const s16x8*)&Bs[cur][(wc * 64 + ni * 16 + cc) * 32 + g * 8];
    #pragma unroll
    for (int mi = 0; mi < 4; ++mi)
      #pragma unroll
      for (int ni = 0; ni < 4; ++ni)
        mfma16x16x32(acc[mi][ni], af[mi], bfr[ni]);
    __syncthreads();                     // drains vmcnt: next buffer staged; cur free to overwrite
    cur ^= 1;
  }

  float bval[4];
  #pragma unroll
  for (int ni = 0; ni < 4; ++ni) bval[ni] = bias[n0 + wc * 64 + ni * 16 + cc];

  #pragma unroll
  for (int mi = 0; mi < 4; ++mi) {
    #pragma unroll
    for (int r = 0; r < 4; ++r) {
      const int row = m0 + wr * 64 + mi * 16 + g * 4 + r;
      size_t obase;
      if constexpr (MODE == 2) {
        int b = row / 3136; int rem = row - b * 3136;
        int win = rem / 49; int n = rem - win * 49;
        int wh = win >> 3, ww = win & 7;
        int i = n / 7, j = n - i * 7;
        int hh = wh * 7 + i + 3; if (hh >= 56) hh -= 56;
        int wp = ww * 7 + j + 3; if (wp >= 56) wp -= 56;
        obase = ((size_t)b * 3136 + (size_t)hh * 56 + wp) * 512;
      } else {
        obase = (size_t)row * N;
      }
      #pragma unroll
      for (int ni = 0; ni < 4; ++ni) {
        const int col = n0 + wc * 64 + ni * 16 + cc;
        float v = acc[mi][ni][r] + bval[ni];
        if constexpr (MODE == 0) {
          outb[obase + col] = f2bf(v);
        } else if constexpr (MODE == 1) {
          outb[obase + col] = f2bf(0.5f * v * (1.0f + erff(v * 0.7071067811865475f)));
        } else {
          outf[obase + col] = residf[obase + col] + v;
        }
      }
    }
  }
}

// ---------------------------------------------------------------------------
// Windowed attention: one wave per (window, head). N=49 (padded 64), HD=32.
// qkv layout per token (chunk-local): [Q(16x32) | K(16x32) | V(16x32)] = 1536.
// wgBase: first global window of this chunk; o indexed by GLOBAL window.
// ---------------------------------------------------------------------------
__device__ __forceinline__ int regcls(int a){ return a < 49 ? 0 : (a < 53 ? 1 : 2); }

__launch_bounds__(64)
__global__ void attn49(const u16* __restrict__ qkv, const float* __restrict__ rpbt,
                       u16* __restrict__ o, int wgBase)
{
  const int unit = blockIdx.x;
  const int wgl = unit >> 4;          // chunk-local window
  const int wg  = wgBase + wgl;       // global window 0..1023
  const int h  = unit & 15;           // head
  const int win = wg & 63;
  const int wh = win >> 3, ww = win & 7;
  const int l = threadIdx.x;
  const int cc = l & 15, g = l >> 4;

  __shared__ u16 P[64 * 72];          // softmax probs, padded stride 72
  __shared__ u16 Vt[32 * 72];         // V transposed [d][k], padded stride 72

  const u16* qb = qkv + (size_t)wgl * 49 * 1536 + h * 32;

  s16x8 qf[4], kf[4];
  #pragma unroll
  for (int mi = 0; mi < 4; ++mi){ int m = mi * 16 + cc; int t = m < 49 ? m : 48;
    qf[mi] = *(const s16x8*)(qb + (size_t)t * 1536 + g * 8); }
  #pragma unroll
  for (int ni = 0; ni < 4; ++ni){ int n = ni * 16 + cc; int t = n < 49 ? n : 48;
    kf[ni] = *(const s16x8*)(qb + 512 + (size_t)t * 1536 + g * 8); }

  { // stage V^T: lane l owns k-row l (clamped)
    int t = l < 49 ? l : 48;
    const u16* vp = qb + 1024 + (size_t)t * 1536;
    s16x8 va = *(const s16x8*)(vp);
    s16x8 vb_ = *(const s16x8*)(vp + 8);
    s16x8 vc = *(const s16x8*)(vp + 16);
    s16x8 vd = *(const s16x8*)(vp + 24);
    #pragma unroll
    for (int d = 0; d < 8; ++d){
      Vt[(d     ) * 72 + l] = (u16)va[d];
      Vt[(d +  8) * 72 + l] = (u16)vb_[d];
      Vt[(d + 16) * 72 + l] = (u16)vc[d];
      Vt[(d + 24) * 72 + l] = (u16)vd[d];
    }
  }

  f32x4 s[4][4] = {};
  #pragma unroll
  for (int mi = 0; mi < 4; ++mi)
    #pragma unroll
    for (int ni = 0; ni < 4; ++ni)
      mfma16x16x32(s[mi][ni], qf[mi], kf[ni]);

  // per-lane column metadata (n = ni*16 + cc)
  int xn[4], yn[4], ncl[4]; bool nval[4];
  #pragma unroll
  for (int ni = 0; ni < 4; ++ni){
    int n = ni * 16 + cc; nval[ni] = (n < 49);
    int t = n < 49 ? n : 48;
    yn[ni] = t / 7; xn[ni] = t - yn[ni] * 7;
    ncl[ni] = regcls(wh * 7 + yn[ni]) * 3 + regcls(ww * 7 + xn[ni]);
  }

  const float SCL = 0.17677669529663687f;   // 32^-0.5
  #pragma unroll
  for (int mi = 0; mi < 4; ++mi){
    #pragma unroll
    for (int r = 0; r < 4; ++r){
      int m = mi * 16 + g * 4 + r;
      int mt = m < 49 ? m : 48;
      int ym = mt / 7, xm = mt - ym * 7;
      int mcl = regcls(wh * 7 + ym) * 3 + regcls(ww * 7 + xm);
      float vals[4];
      #pragma unroll
      for (int ni = 0; ni < 4; ++ni){
        // reference index quirk: idx = (dx+6)*13 + (dy+6), x = tok%7, y = tok/7
        int idx = (xm - xn[ni] + 6) * 13 + (ym - yn[ni] + 6);
        float v = s[mi][ni][r] * SCL + rpbt[idx * 16 + h];
        if (ncl[ni] != mcl) v -= 100.f;
        if (!nval[ni]) v = -1e9f;
        vals[ni] = v;
      }
      float mx = fmaxf(fmaxf(vals[0], vals[1]), fmaxf(vals[2], vals[3]));
      #pragma unroll
      for (int d2 = 1; d2 < 16; d2 <<= 1) mx = fmaxf(mx, __shfl_xor(mx, d2));
      float e[4]; float sm = 0.f;
      #pragma unroll
      for (int ni = 0; ni < 4; ++ni){ e[ni] = __expf(vals[ni] - mx); sm += e[ni]; }
      #pragma unroll
      for (int d2 = 1; d2 < 16; d2 <<= 1) sm += __shfl_xor(sm, d2);
      float inv = 1.f / sm;
      #pragma unroll
      for (int ni = 0; ni < 4; ++ni) P[m * 72 + ni * 16 + cc] = f2bf(e[ni] * inv);
    }
  }
  __syncthreads();

  f32x4 oa[4][2] = {};
  #pragma unroll
  for (int kk = 0; kk < 2; ++kk){
    s16x8 pa[4], vb[2];
    #pragma unroll
    for (int mi = 0; mi < 4; ++mi) pa[mi] = *(const s16x8*)&P[(mi * 16 + cc) * 72 + kk * 32 + g * 8];
    #pragma unroll
    for (int ni = 0; ni < 2; ++ni) vb[ni] = *(const s16x8*)&Vt[(ni * 16 + cc) * 72 + kk * 32 + g * 8];
    #pragma unroll
    for (int mi = 0; mi < 4; ++mi)
      #pragma unroll
      for (int ni = 0; ni < 2; ++ni)
        mfma16x16x32(oa[mi][ni], pa[mi], vb[ni]);
  }

  const size_t tb = (size_t)wg * 49;
  #pragma unroll
  for (int mi = 0; mi < 4; ++mi)
    #pragma unroll
    for (int r = 0; r < 4; ++r){
      int m = mi * 16 + g * 4 + r;
      if (m < 49){
        size_t ob = (tb + m) * 512 + h * 32;
        o[ob + cc]      = f2bf(oa[mi][0][r]);
        o[ob + 16 + cc] = f2bf(oa[mi][1][r]);
      }
    }
}

// ---------------------------------------------------------------------------
// Launch — f32 in/out, bf16 intermediates, ws-adaptive M-chunking
// ---------------------------------------------------------------------------
extern "C" void kernel_launch(void* const* d_in, const int* in_sizes, int n_in,
                              void* d_out, int out_size, void* d_ws, size_t ws_size,
                              hipStream_t stream)
{
  const float* x      = (const float*)d_in[0];
  const float* ln1_s  = (const float*)d_in[1];
  const float* ln1_b  = (const float*)d_in[2];
  const float* qkv_w  = (const float*)d_in[3];
  const float* qkv_b  = (const float*)d_in[4];
  const float* rpbt   = (const float*)d_in[5];
  const float* proj_w = (const float*)d_in[6];
  const float* proj_b = (const float*)d_in[7];
  const float* ln2_s  = (const float*)d_in[8];
  const float* ln2_b  = (const float*)d_in[9];
  const float* fc1_w  = (const float*)d_in[10];
  const float* fc1_b  = (const float*)d_in[11];
  const float* fc2_w  = (const float*)d_in[12];
  const float* fc2_b  = (const float*)d_in[13];
  float* outF = (float*)d_out;

  const size_t BUFA_B = 51380224ull;             // 50176*512*2 (bf16)
  const size_t WTS_B  = 6291456ull;              // transposed bf16 weights
  // pick chunk count: bufB = (50176/CH)*2048*2 bytes
  int CH = 8;
  for (int c : {1, 2, 4}) {
    size_t bufb = (50176ull / c) * 4096ull;
    if (ws_size >= BUFA_B + bufb + WTS_B) { CH = c; break; }
  }
  const int MCH = 50176 / CH;                    // rows per chunk (multiple of 128)
  const int TCH = MCH / 128;                     // row-tiles per chunk
  const int WCH = 1024 / CH;                     // windows per chunk
  const size_t BUFB_B = (size_t)MCH * 4096ull;

  char* w = (char*)d_ws;
  u16* bufA = (u16*)(w);                         // hwin -> attn_out -> ln2_out (bf16, full)
  u16* bufB = (u16*)(w + BUFA_B);                // per-chunk qkv / gelu act (bf16, union)
  u16* qkvT  = (u16*)(w + BUFA_B + BUFB_B);
  u16* projT = qkvT + 786432;
  u16* fc1T  = projT + 262144;
  u16* fc2T  = fc1T + 1048576;

  // weight transposes + f32->bf16 ([K,N] -> [N,K])
  transpose_w<<<dim3(1536/32, 512/32),  256, 0, stream>>>(qkv_w,  qkvT, 512, 1536);
  transpose_w<<<dim3( 512/32, 512/32),  256, 0, stream>>>(proj_w, projT, 512, 512);
  transpose_w<<<dim3(2048/32, 512/32),  256, 0, stream>>>(fc1_w,  fc1T, 512, 2048);
  transpose_w<<<dim3( 512/32, 2048/32), 256, 0, stream>>>(fc2_w,  fc2T, 2048, 512);

  // LN1 + cyclic shift + window partition (f32 -> bf16 windowed)
  ln_win<true><<<12544, 256, 0, stream>>>(x, ln1_s, ln1_b, bufA);

  // chunked: QKV GEMM -> windowed attention (attn writes back into bufA rows of its chunk)
  for (int c = 0; c < CH; ++c) {
    gemm_bt<0><<<dim3(12, TCH), 256, 0, stream>>>(bufA + (size_t)c * MCH * 512, qkvT, qkv_b,
                                                  bufB, nullptr, nullptr, 1536, 512);
    attn49<<<WCH * 16, 64, 0, stream>>>(bufB, rpbt, bufA, c * WCH);
  }

  // proj GEMM + window reverse + unshift + residual(x) -> x1 (f32, in d_out)
  gemm_bt<2><<<dim3(4, 392), 256, 0, stream>>>(bufA, projT, proj_b, nullptr, outF, x, 512, 512);

  // LN2 (reads f32 x1 from d_out)
  ln_win<false><<<12544, 256, 0, stream>>>(outF, ln2_s, ln2_b, bufA);

  // chunked: FC1+GELU -> FC2+residual (x1 aliased in d_out, same-thread R-then-W)
  for (int c = 0; c < CH; ++c) {
    gemm_bt<1><<<dim3(16, TCH), 256, 0, stream>>>(bufA + (size_t)c * MCH * 512, fc1T, fc1_b,
                                                  bufB, nullptr, nullptr, 2048, 512);
    gemm_bt<3><<<dim3(4, TCH), 256, 0, stream>>>(bufB, fc2T, fc2_b, nullptr,
                                                 outF + (size_t)c * MCH * 512,
                                                 outF + (size_t)c * MCH * 512, 512, 2048);
  }
}